// Round 1
// baseline (113.794 us; speedup 1.0000x reference)
//
#include <hip/hip_runtime.h>

// Fused CNN, conv2 via bf16 MFMA (16x16x32).
// R4: (a) stage-1 conv via v_pk_fma_f32: fp32 peak on CDNA4 is 2 FMA/lane/cyc and
//         only packed f32 reaches it (compiler never auto-packs). Conv columns
//         (xx, xx+7) are paired into f32x2; rows kept as 8 aligned pairs
//         {in[k], in[k+7]} so every tap reads an aligned VGPR pair.
//         117 scalar FMA/row -> 54 pk + 9 scalar (col 6 leftover).
//     (b) LDS bank-conflict fixes: cbuf stride 100->101 dwords (100 == 4 mod 32
//         put all 64 lanes of stage-2b reads on 8 banks = 8-way conflict),
//         h2t stride 64->65 (write conflict 4-way -> ~2-way).
//         LDS 29696 -> 30016 B, still 5 blocks/CU.

typedef __attribute__((ext_vector_type(8))) short short8;   // 8 x bf16 (4 VGPRs)
typedef __attribute__((ext_vector_type(4))) float f32x4;
typedef __attribute__((ext_vector_type(2))) float f32x2;

__device__ inline short f2bf(float f) {   // fp32 -> bf16, round-to-nearest-even
    union { float f; unsigned u; } v; v.f = f;
    unsigned r = (v.u + 0x7FFFu + ((v.u >> 16) & 1u)) >> 16;
    return (short)r;
}

__device__ inline void pk_fma(f32x2& d, f32x2 a, f32x2 b) {
    asm("v_pk_fma_f32 %0, %1, %2, %0" : "+v"(d) : "v"(a), "v"(b));
}
__device__ inline f32x2 pk_mul(f32x2 a, f32x2 b) {
    f32x2 d; asm("v_pk_mul_f32 %0, %1, %2" : "=v"(d) : "v"(a), "v"(b)); return d;
}
__device__ inline void pk_add(f32x2& d, f32x2 a) {
    asm("v_pk_add_f32 %0, %1, %0" : "+v"(d) : "v"(a));
}

// w2r[s][cout][cin] (bf16), s = ky*3+kx: MFMA A-fragments contiguous in cin.
__global__ __launch_bounds__(256) void prep_w2(const float* __restrict__ w2,
                                               short* __restrict__ w2r) {
    int i = blockIdx.x * 256 + threadIdx.x;      // 9*64*64 = 36864
    if (i >= 36864) return;
    int s = i >> 12, cout = (i >> 6) & 63, cin = i & 63;
    w2r[i] = f2bf(w2[cout * 576 + cin * 9 + s]);
}

__global__ __launch_bounds__(256) void convnet_fused(
    const float* __restrict__ x,   // [B,1,28,28]
    const float* __restrict__ w1,  // [64,1,3,3]
    const float* __restrict__ b1,  // [64]
    const short* __restrict__ w2r, // [9][64][64] bf16 (prep)
    const float* __restrict__ b2,  // [64]
    const float* __restrict__ w3,  // [10,64,4,4]
    const float* __restrict__ b3,  // [10]
    float* __restrict__ out)       // [B,10]
{
    // Overlay plan (floats):
    //   [0..5184)    h1t bf16 [144 pos][72 cin-stride]  -> later cbuf fp32 [64][101] ([0..6464))
    //   [5184..5968) img 28x28                          -> (absorbed by cbuf)
    //   [6464..7504) h2t fp32 [16 pos][65 stride]
    //   [0..160)     stage-3 partials (cbuf dead by then)
    __shared__ float lds_f[7504];                // 30016 B -> 5 blocks/CU
    short* h1t  = (short*)lds_f;
    float* img  = lds_f + 5184;
    float* cbuf = lds_f;                         // conv2buf fp32 [64][101]
    float* h2t  = lds_f + 6464;
    float* prt  = lds_f;

    const int n_img = blockIdx.x;
    const int t = threadIdx.x;
    const int c = t >> 2;        // 0..63
    const int q = t & 3;         // quadrant

    // ---- load input image ----
    const float* img_g = x + (size_t)n_img * 784;
    for (int i = t; i < 784; i += 256) img[i] = img_g[i];
    __syncthreads();

    // ---- stage 1: conv1 + pool 3x3 s2 + relu -> h1t[pos][c] (bf16) ----
    // packed pairs: columns (xx, xx+7); row storage ring[.][k] = {in[k], in[k+7]}
    {
        const int oy = (q >> 1) * 6, ox = (q & 1) * 6;   // pooled quadrant origin
        const int ib = (2 * oy) * 28 + (2 * ox);         // input region origin

        f32x2 wp[9];
        #pragma unroll
        for (int k = 0; k < 9; ++k) { const float ww = w1[c * 9 + k]; wp[k] = (f32x2){ww, ww}; }
        const float bias = b1[c];
        const f32x2 bias2 = (f32x2){bias, bias};

        f32x2 ring[3][8];
        float cm[3][6];                                  // colmax ring (3 conv rows)
        #pragma unroll
        for (int rr = 0; rr < 2; ++rr)
            #pragma unroll
            for (int k = 0; k < 8; ++k)
                ring[rr][k] = (f32x2){ img[ib + rr * 28 + k], img[ib + rr * 28 + k + 7] };

        #define FOLD(col, val) do { \
            if (((col) & 1) == 0) { \
                if ((col) >= 2)  cm[R0][(col)/2 - 1] = fmaxf(cm[R0][(col)/2 - 1], (val)); \
                if ((col) <= 10) cm[R0][(col)/2]     = fmaxf(cm[R0][(col)/2], (val)); \
            } else { cm[R0][(col)/2] = fmaxf(cm[R0][(col)/2], (val)); } } while (0)

        #pragma unroll
        for (int r = 0; r < 13; ++r) {                   // conv rows, computed once
            const int R0 = r % 3, R1 = (r + 1) % 3, R2 = (r + 2) % 3;
            #pragma unroll
            for (int k = 0; k < 8; ++k)
                ring[R2][k] = (f32x2){ img[ib + (r + 2) * 28 + k],
                                       img[ib + (r + 2) * 28 + k + 7] };
            #pragma unroll
            for (int p = 0; p < 6; ++p) cm[R0][p] = -1e30f;

            #pragma unroll
            for (int xx = 0; xx < 6; ++xx) {             // pairs (xx, xx+7)
                f32x2 a2 = pk_mul(ring[R0][xx], wp[0]);
                pk_fma(a2, ring[R0][xx + 1], wp[1]);
                pk_fma(a2, ring[R0][xx + 2], wp[2]);
                pk_fma(a2, ring[R1][xx],     wp[3]);
                pk_fma(a2, ring[R1][xx + 1], wp[4]);
                pk_fma(a2, ring[R1][xx + 2], wp[5]);
                pk_fma(a2, ring[R2][xx],     wp[6]);
                pk_fma(a2, ring[R2][xx + 1], wp[7]);
                pk_fma(a2, ring[R2][xx + 2], wp[8]);
                pk_add(a2, bias2);
                FOLD(xx, a2.x);
                FOLD(xx + 7, a2.y);
            }
            {   // conv col 6 (unpaired): in[6]=ring[.][6].x, in[7]=ring[.][7].x, in[8]=ring[.][1].y
                float a = bias;
                a += ring[R0][6].x * wp[0].x + ring[R0][7].x * wp[1].x + ring[R0][1].y * wp[2].x;
                a += ring[R1][6].x * wp[3].x + ring[R1][7].x * wp[4].x + ring[R1][1].y * wp[5].x;
                a += ring[R2][6].x * wp[6].x + ring[R2][7].x * wp[7].x + ring[R2][1].y * wp[8].x;
                FOLD(6, a);
            }
            if (r >= 2 && (r & 1) == 0) {                // pooled row py = r/2 - 1 complete
                const int py = r / 2 - 1;
                #pragma unroll
                for (int px = 0; px < 6; ++px) {
                    float m = fmaxf(fmaxf(cm[0][px], cm[1][px]), cm[2][px]);
                    h1t[((oy + py) * 12 + ox + px) * 72 + c] = f2bf(fmaxf(m, 0.0f));
                }
            }
        }
        #undef FOLD
    }
    __syncthreads();

    // ---- stage 2: conv2 as MFMA GEMM (M=64 cout, N=100 pad 112, K=576) ----
    const int wv = t >> 6, lane = t & 63;
    const int quad = lane >> 4, mrow = lane & 15;
    {
        int base_el[7];
        #pragma unroll
        for (int nt = 0; nt < 7; ++nt) {
            int n = nt * 16 + mrow; if (n > 99) n = 99;   // clamp pad cols (discarded)
            int y = n / 10, xx = n - y * 10;
            base_el[nt] = (y * 12 + xx) * 72;
        }
        f32x4 acc[7];
        #pragma unroll
        for (int nt = 0; nt < 7; ++nt) acc[nt] = (f32x4){0.f, 0.f, 0.f, 0.f};

        #pragma unroll
        for (int ks = 0; ks < 18; ++ks) {
            const int s = ks >> 1, h = ks & 1;
            const int ky = s / 3, kx = s - ky * 3;
            const short8 a = *(const short8*)(w2r + s * 4096 + (wv * 16 + mrow) * 64
                                              + h * 32 + quad * 8);
            #pragma unroll
            for (int nt = 0; nt < 7; ++nt) {
                const short8 b = *(const short8*)(h1t + base_el[nt]
                                                  + (ky * 12 + kx) * 72 + h * 32 + quad * 8);
                acc[nt] = __builtin_amdgcn_mfma_f32_16x16x32_bf16(a, b, acc[nt], 0, 0, 0);
            }
        }
        __syncthreads();   // all h1t + img reads done; overlay region reusable
        // epilogue: D[row=quad*4+r][col=mrow] -> cbuf[cout][pos] + bias
        #pragma unroll
        for (int nt = 0; nt < 7; ++nt) {
            const int n = nt * 16 + mrow;
            if (n < 100) {
                #pragma unroll
                for (int r = 0; r < 4; ++r) {
                    const int cout = wv * 16 + quad * 4 + r;
                    cbuf[cout * 101 + n] = acc[nt][r] + b2[cout];
                }
            }
        }
    }
    __syncthreads();

    // ---- stage 2b: pool 3x3 s2 + relu -> h2t[pos*65+cin] fp32 ----
    {
        const float* cb = cbuf + c * 101;
        #pragma unroll
        for (int k = 0; k < 4; ++k) {
            const int pos = q * 4 + k;
            const int py = pos >> 2, px = pos & 3;
            float m = -1e30f;
            #pragma unroll
            for (int a = 0; a < 3; ++a)
                #pragma unroll
                for (int b = 0; b < 3; ++b)
                    m = fmaxf(m, cb[(2 * py + a) * 10 + (2 * px + b)]);
            h2t[pos * 65 + c] = fmaxf(m, 0.0f);
        }
    }
    __syncthreads();

    // ---- stage 3: conv3 4x4 -> out[n][10] ----
    if (t < 160) {
        const int o = t >> 4, l = t & 15;
        const float* w3o = w3 + o * 1024;
        float s = 0.0f;
        #pragma unroll
        for (int cc = 0; cc < 4; ++cc) {
            const int cin = l * 4 + cc;
            const float4 wv4a = *(const float4*)(w3o + cin * 16);
            const float4 wv4b = *(const float4*)(w3o + cin * 16 + 4);
            const float4 wv4c = *(const float4*)(w3o + cin * 16 + 8);
            const float4 wv4d = *(const float4*)(w3o + cin * 16 + 12);
            const float* hh = h2t + cin;           // h2t[k*65+cin]
            s += hh[0*65] * wv4a.x + hh[1*65] * wv4a.y + hh[2*65] * wv4a.z + hh[3*65] * wv4a.w;
            s += hh[4*65] * wv4b.x + hh[5*65] * wv4b.y + hh[6*65] * wv4b.z + hh[7*65] * wv4b.w;
            s += hh[8*65] * wv4c.x + hh[9*65] * wv4c.y + hh[10*65] * wv4c.z + hh[11*65] * wv4c.w;
            s += hh[12*65] * wv4d.x + hh[13*65] * wv4d.y + hh[14*65] * wv4d.z + hh[15*65] * wv4d.w;
        }
        prt[t] = s;   // cbuf dead (pool reads barriered above)
    }
    __syncthreads();
    if (t < 10) {
        float s = b3[t];
        #pragma unroll
        for (int l = 0; l < 16; ++l) s += prt[t * 16 + l];
        out[(size_t)n_img * 10 + t] = s;
    }
}

extern "C" void kernel_launch(void* const* d_in, const int* in_sizes, int n_in,
                              void* d_out, int out_size, void* d_ws, size_t ws_size,
                              hipStream_t stream) {
    const float* x  = (const float*)d_in[0];
    const float* w1 = (const float*)d_in[1];
    const float* b1 = (const float*)d_in[2];
    const float* w2 = (const float*)d_in[3];
    const float* b2 = (const float*)d_in[4];
    const float* w3 = (const float*)d_in[5];
    const float* b3 = (const float*)d_in[6];
    float* out = (float*)d_out;
    short* w2r = (short*)d_ws;            // 36864 bf16 = 73728 B

    const int B = in_sizes[0] / 784;      // 2048
    prep_w2<<<144, 256, 0, stream>>>(w2, w2r);
    convnet_fused<<<B, 256, 0, stream>>>(x, w1, b1, w2r, b2, w3, b3, out);
}